// Round 2
// baseline (228.231 us; speedup 1.0000x reference)
//
#include <hip/hip_runtime.h>

typedef short bf16x8 __attribute__((ext_vector_type(8)));
typedef float f32x4 __attribute__((ext_vector_type(4)));
typedef float fvec4 __attribute__((ext_vector_type(4)));
typedef unsigned short u16;

#define MFMA_BF16 __builtin_amdgcn_mfma_f32_16x16x32_bf16

static __device__ __forceinline__ u16 f2bf(float f) {
  union { float f; unsigned u; } v; v.f = f;
  return (u16)((v.u + 0x7FFFu + ((v.u >> 16) & 1u)) >> 16);  // RNE
}

// ---------------- Kernel 0: W transpose -> Wt[192][1024] bf16 (row m*64+n = W_m[:, n])
__global__ __launch_bounds__(256) void wt_kernel(const float* __restrict__ Wq,
                                                 const float* __restrict__ Wk,
                                                 const float* __restrict__ Wv,
                                                 u16* __restrict__ Wt) {
  const int nrow = blockIdx.x;               // 0..191
  const int m = nrow >> 6, n = nrow & 63;
  const float* W = (m == 0) ? Wq : ((m == 1) ? Wk : Wv);
  for (int k = threadIdx.x; k < 1024; k += 256)
    Wt[(size_t)nrow * 1024 + k] = f2bf(W[(size_t)k * 64 + n]);
}

// ---------------- Kernel 1: fused QKV projection (bf16 MFMA, fp32 accum)
// Block = 4 waves; wave w owns 16 rows; 12 N-subtiles = Q(4) K(4) V(4).
__global__ __launch_bounds__(256) void qkv_proj(const float* __restrict__ x,
                                                const u16* __restrict__ Wt,
                                                u16* __restrict__ Qb,
                                                u16* __restrict__ Kb,
                                                u16* __restrict__ Vb) {
  const int w = threadIdx.x >> 6, l = threadIdx.x & 63;
  const int lane16 = l & 15, laneHi = l >> 4;
  const int rowA = blockIdx.x * 64 + w * 16 + lane16;
  const float* xrow = x + (size_t)rowA * 1024;

  const f32x4 fzero = {0.f, 0.f, 0.f, 0.f};
  f32x4 acc[12];
#pragma unroll
  for (int i = 0; i < 12; ++i) acc[i] = fzero;

  for (int kk = 0; kk < 32; ++kk) {
    const int kb = kk * 32 + 8 * laneHi;     // contiguous 8 k-elements per lane
    fvec4 f0 = *(const fvec4*)(xrow + kb);
    fvec4 f1 = *(const fvec4*)(xrow + kb + 4);
    bf16x8 a;
#pragma unroll
    for (int j = 0; j < 4; ++j) { a[j] = (short)f2bf(f0[j]); a[j + 4] = (short)f2bf(f1[j]); }
#pragma unroll
    for (int nt = 0; nt < 12; ++nt) {
      bf16x8 bfrag = *(const bf16x8*)(Wt + (size_t)(nt * 16 + lane16) * 1024 + kb);
      acc[nt] = MFMA_BF16(a, bfrag, acc[nt], 0, 0, 0);
    }
  }

  const int rowBase = blockIdx.x * 64 + w * 16 + laneHi * 4;
#pragma unroll
  for (int m = 0; m < 3; ++m) {
    u16* Ob = (m == 0) ? Qb : ((m == 1) ? Kb : Vb);
    const float s = (m == 0) ? 0.125f : 1.0f;   // fold 1/sqrt(D) into Q
#pragma unroll
    for (int ns = 0; ns < 4; ++ns) {
#pragma unroll
      for (int r = 0; r < 4; ++r)
        Ob[(size_t)(rowBase + r) * 64 + ns * 16 + lane16] = f2bf(acc[m * 4 + ns][r] * s);
    }
  }
}

// ---------------- Kernel 2: causal flash attention
// Block = 4 waves: waves 0,1 -> q-tile p (32 rows), waves 2,3 -> q-tile 127-p.
// KV tile = 64 keys staged in LDS (V transposed). Online softmax in-register.
#define KLD 72   // padded leading dim (bf16) -> 144B rows, <=2-way bank conflicts

__global__ __launch_bounds__(256) void attn_kernel(const u16* __restrict__ Qb,
                                                   const u16* __restrict__ Kb,
                                                   const u16* __restrict__ Vb,
                                                   float* __restrict__ out) {
  __shared__ __align__(16) u16 shK[64 * KLD];
  __shared__ __align__(16) u16 shV[64 * KLD];     // transposed: [d][key]
  __shared__ __align__(16) u16 shP[4 * 16 * KLD]; // per-wave P scratch

  const int tid = threadIdx.x;
  const int w = tid >> 6, l = tid & 63;
  const int lane16 = l & 15, laneHi = l >> 4;
  const int b = blockIdx.x >> 6, p = blockIdx.x & 63;
  const int qt = (w < 2) ? p : (127 - p);
  const int q0 = qt * 32 + (w & 1) * 16;          // this wave's first q row
  const int bT = b * 4096;
  const int ntW = (q0 + 79) >> 6;                 // KV tiles this wave needs
  const int maxNt = ((127 - p) * 32 + 16 + 79) >> 6;  // block max

  const u16* qrow = Qb + (size_t)(bT + q0 + lane16) * 64;
  const bf16x8 qf0 = *(const bf16x8*)(qrow + 8 * laneHi);
  const bf16x8 qf1 = *(const bf16x8*)(qrow + 32 + 8 * laneHi);

  const f32x4 fzero = {0.f, 0.f, 0.f, 0.f};
  f32x4 o[4];
#pragma unroll
  for (int i = 0; i < 4; ++i) o[i] = fzero;
  float mrow[4] = {-INFINITY, -INFINITY, -INFINITY, -INFINITY};
  float lrow[4] = {0.f, 0.f, 0.f, 0.f};

  const int srow = tid >> 3, sc0 = (tid & 7) * 8; // staging coords (rows srow, srow+32)
  const int pwb = w * 16 * KLD;

  for (int t = 0; t < maxNt; ++t) {
    __syncthreads();
#pragma unroll
    for (int rr = 0; rr < 2; ++rr) {               // 2 rows/thread: 64 rows total
      const int row = srow + rr * 32;
      uint4 kvec = *(const uint4*)(Kb + (size_t)(bT + t * 64 + row) * 64 + sc0);
      *(uint4*)&shK[row * KLD + sc0] = kvec;
      uint4 vvec = *(const uint4*)(Vb + (size_t)(bT + t * 64 + row) * 64 + sc0);
      const u16* vp = (const u16*)&vvec;
#pragma unroll
      for (int j = 0; j < 8; ++j) shV[(sc0 + j) * KLD + row] = vp[j];
    }
    __syncthreads();

    if (t < ntW) {
      // ---- S = Q K^T (scaled Q already)
      f32x4 sc[4];
#pragma unroll
      for (int ct = 0; ct < 4; ++ct) {
        f32x4 a = fzero;
        a = MFMA_BF16(qf0, *(const bf16x8*)&shK[(ct * 16 + lane16) * KLD + 8 * laneHi], a, 0, 0, 0);
        a = MFMA_BF16(qf1, *(const bf16x8*)&shK[(ct * 16 + lane16) * KLD + 32 + 8 * laneHi], a, 0, 0, 0);
        sc[ct] = a;
      }
      // ---- causal mask (only near-diagonal tiles)
      if (t * 64 + 63 > q0) {
#pragma unroll
        for (int ct = 0; ct < 4; ++ct)
#pragma unroll
          for (int r = 0; r < 4; ++r) {
            const int col = t * 64 + ct * 16 + lane16;
            const int row = q0 + laneHi * 4 + r;
            if (col > row) sc[ct][r] = -INFINITY;
          }
      }
      // ---- online softmax (rows live in 16-lane groups)
      float mt[4] = {-INFINITY, -INFINITY, -INFINITY, -INFINITY};
#pragma unroll
      for (int ct = 0; ct < 4; ++ct)
#pragma unroll
        for (int r = 0; r < 4; ++r) mt[r] = fmaxf(mt[r], sc[ct][r]);
#pragma unroll
      for (int d = 1; d < 16; d <<= 1)
#pragma unroll
        for (int r = 0; r < 4; ++r) mt[r] = fmaxf(mt[r], __shfl_xor(mt[r], d));

      float alpha[4], rs[4];
#pragma unroll
      for (int r = 0; r < 4; ++r) {
        const float mn = fmaxf(mrow[r], mt[r]);
        alpha[r] = __expf(mrow[r] - mn);
        mrow[r] = mn;
        rs[r] = 0.f;
      }
#pragma unroll
      for (int ct = 0; ct < 4; ++ct)
#pragma unroll
        for (int r = 0; r < 4; ++r) {
          const float pv = __expf(sc[ct][r] - mrow[r]);
          rs[r] += pv;
          shP[pwb + (laneHi * 4 + r) * KLD + ct * 16 + lane16] = f2bf(pv);
        }
#pragma unroll
      for (int d = 1; d < 16; d <<= 1)
#pragma unroll
        for (int r = 0; r < 4; ++r) rs[r] += __shfl_xor(rs[r], d);
#pragma unroll
      for (int r = 0; r < 4; ++r) lrow[r] = lrow[r] * alpha[r] + rs[r];
#pragma unroll
      for (int nt = 0; nt < 4; ++nt)
#pragma unroll
        for (int r = 0; r < 4; ++r) o[nt][r] *= alpha[r];

      asm volatile("s_waitcnt lgkmcnt(0)" ::: "memory");  // P writes -> P reads (same wave)

      // ---- O += P V
#pragma unroll
      for (int kk = 0; kk < 2; ++kk) {
        bf16x8 pa = *(const bf16x8*)&shP[pwb + lane16 * KLD + kk * 32 + 8 * laneHi];
#pragma unroll
        for (int nt = 0; nt < 4; ++nt) {
          bf16x8 vb = *(const bf16x8*)&shV[(nt * 16 + lane16) * KLD + kk * 32 + 8 * laneHi];
          o[nt] = MFMA_BF16(pa, vb, o[nt], 0, 0, 0);
        }
      }
    }
  }

  float inv[4];
#pragma unroll
  for (int r = 0; r < 4; ++r) inv[r] = 1.0f / lrow[r];
#pragma unroll
  for (int nt = 0; nt < 4; ++nt)
#pragma unroll
    for (int r = 0; r < 4; ++r)
      out[(size_t)(bT + q0 + laneHi * 4 + r) * 64 + nt * 16 + lane16] = o[nt][r] * inv[r];
}

extern "C" void kernel_launch(void* const* d_in, const int* in_sizes, int n_in,
                              void* d_out, int out_size, void* d_ws, size_t ws_size,
                              hipStream_t stream) {
  const float* x  = (const float*)d_in[0];
  const float* Wq = (const float*)d_in[1];
  const float* Wk = (const float*)d_in[2];
  const float* Wv = (const float*)d_in[3];
  float* out = (float*)d_out;

  char* ws = (char*)d_ws;
  u16* Wt = (u16*)ws;                                   // 192*1024*2   = 384 KiB
  u16* Qb = (u16*)(ws + 393216);                        // 16384*64*2   = 2 MiB
  u16* Kb = (u16*)(ws + 393216 + 2097152);
  u16* Vb = (u16*)(ws + 393216 + 2 * 2097152);          // total ~6.4 MiB

  wt_kernel<<<192, 256, 0, stream>>>(Wq, Wk, Wv, Wt);
  qkv_proj<<<256, 256, 0, stream>>>(x, Wt, Qb, Kb, Vb);
  attn_kernel<<<256, 256, 0, stream>>>(Qb, Kb, Vb, out);
}

// Round 3
// 163.573 us; speedup vs baseline: 1.3953x; 1.3953x over previous
//
#include <hip/hip_runtime.h>

typedef short bf16x8 __attribute__((ext_vector_type(8)));
typedef float f32x4 __attribute__((ext_vector_type(4)));
typedef float fvec4 __attribute__((ext_vector_type(4)));
typedef unsigned short u16;
typedef unsigned int u32;

#define MFMA_BF16 __builtin_amdgcn_mfma_f32_16x16x32_bf16

static __device__ __forceinline__ u16 f2bf(float f) {
  union { float f; unsigned u; } v; v.f = f;
  return (u16)((v.u + 0x7FFFu + ((v.u >> 16) & 1u)) >> 16);  // RNE
}
static __device__ __forceinline__ u32 pack2bf(float a, float b) {
  return (u32)f2bf(a) | ((u32)f2bf(b) << 16);
}

// ---------------- Kernel 0: W -> Wt[192][1024] bf16 (row m*64+n = W_m[:, n]); Q scale folded
__global__ __launch_bounds__(256) void wt_kernel(const float* __restrict__ Wq,
                                                 const float* __restrict__ Wk,
                                                 const float* __restrict__ Wv,
                                                 u16* __restrict__ Wt) {
  const int nrow = blockIdx.x;               // 0..191
  const int m = nrow >> 6, n = nrow & 63;
  const float* W = (m == 0) ? Wq : ((m == 1) ? Wk : Wv);
  const float s = (m == 0) ? 0.125f : 1.0f;  // fold 1/sqrt(64) into Wq
  for (int k = threadIdx.x; k < 1024; k += 256)
    Wt[(size_t)nrow * 1024 + k] = f2bf(W[(size_t)k * 64 + n] * s);
}

// ---------------- Kernel 1: QKV projection. Grid 768 = 256 row-tiles x {Q,K,V}.
// m==2 (V) writes TRANSPOSED Vt[64][16384] via swizzled LDS transpose.
__global__ __launch_bounds__(256) void qkv2(const float* __restrict__ x,
                                            const u16* __restrict__ Wt,
                                            u16* __restrict__ Qb,
                                            u16* __restrict__ Kb,
                                            u16* __restrict__ Vt) {
  __shared__ __align__(16) u16 shv[64 * 64];   // 8KB, only used by V blocks
  const int m = blockIdx.x >> 8;               // 0=Q,1=K,2=V
  const int r0 = (blockIdx.x & 255) * 64;
  const int w = threadIdx.x >> 6, l = threadIdx.x & 63;
  const int lane16 = l & 15, laneHi = l >> 4;
  const float* xrow = x + (size_t)(r0 + w * 16 + lane16) * 1024;
  const u16* Wm = Wt + (size_t)m * 64 * 1024;

  const f32x4 fzero = {0.f, 0.f, 0.f, 0.f};
  f32x4 acc[4] = {fzero, fzero, fzero, fzero};

#pragma unroll 2
  for (int kk = 0; kk < 32; ++kk) {
    const int kb = kk * 32 + 8 * laneHi;
    fvec4 f0 = *(const fvec4*)(xrow + kb);
    fvec4 f1 = *(const fvec4*)(xrow + kb + 4);
    bf16x8 a;
#pragma unroll
    for (int j = 0; j < 4; ++j) { a[j] = (short)f2bf(f0[j]); a[j + 4] = (short)f2bf(f1[j]); }
#pragma unroll
    for (int nt = 0; nt < 4; ++nt) {
      bf16x8 bfrag = *(const bf16x8*)(Wm + (size_t)(nt * 16 + lane16) * 1024 + kb);
      acc[nt] = MFMA_BF16(a, bfrag, acc[nt], 0, 0, 0);
    }
  }

  if (m < 2) {
    u16* Ob = (m == 0) ? Qb : Kb;
    const int rowBase = r0 + w * 16 + laneHi * 4;
#pragma unroll
    for (int nt = 0; nt < 4; ++nt)
#pragma unroll
      for (int r = 0; r < 4; ++r)
        Ob[(size_t)(rowBase + r) * 64 + nt * 16 + lane16] = f2bf(acc[nt][r]);
  } else {
    // V: transpose 64x64 tile in LDS (XOR-swizzled 16B chunks), write Vt rows.
    const int qb = w * 16 + laneHi * 4;
#pragma unroll
    for (int nt = 0; nt < 4; ++nt) {
      const int dd = nt * 16 + lane16;
      const u32 xo = (u32)((dd & 7) << 4);
#pragma unroll
      for (int r = 0; r < 4; r += 2) {
        const u32 byte = (u32)(dd * 128 + (qb + r) * 2);
        *(u32*)((char*)shv + (byte ^ xo)) = pack2bf(acc[nt][r], acc[nt][r + 1]);
      }
    }
    __syncthreads();
    const int dd = threadIdx.x >> 2;
    const u32 xo = (u32)((dd & 7) << 4);
#pragma unroll
    for (int i = 0; i < 2; ++i) {
      const int ch = (threadIdx.x & 3) * 2 + i;
      const u32 byte = (u32)(dd * 128 + ch * 16);
      uint4 v = *(const uint4*)((char*)shv + (byte ^ xo));
      *(uint4*)(Vt + (size_t)dd * 16384 + r0 + ch * 8) = v;
    }
  }
}

// ---------------- Kernel 2: causal flash attention, register-direct K/V (no LDS staging)
// Grid 1024 = 4 batches x 256 q-tiles (16 rows), longest tile first.
// 4 waves split the causal KV range into 4 chunks of 64-key units; LDS combine at end.
#define PLD 72

__global__ __launch_bounds__(256) void attn2(const u16* __restrict__ Qb,
                                             const u16* __restrict__ Kb,
                                             const u16* __restrict__ Vt,
                                             float* __restrict__ out) {
  __shared__ __align__(16) u16 shP[4][16 * PLD];   // per-wave P scratch
  __shared__ float shC[3][64][24];                 // waves 1..3 partials for combine

  const int tid = threadIdx.x, w = tid >> 6, l = tid & 63;
  const int lane16 = l & 15, laneHi = l >> 4;
  const int b = blockIdx.x >> 8;
  const int t = 255 - (blockIdx.x & 255);          // longest-first
  const int q0 = t * 16, bT = b * 4096;

  const u16* qrow = Qb + (size_t)(bT + q0 + lane16) * 64;
  const bf16x8 qf0 = *(const bf16x8*)(qrow + 8 * laneHi);
  const bf16x8 qf1 = *(const bf16x8*)(qrow + 32 + 8 * laneHi);

  const int n64 = (t + 4) >> 2;                    // ceil((t+1)/4) 64-key units
  const int s = (n64 * w) >> 2, e = (n64 * (w + 1)) >> 2;

  const f32x4 fzero = {0.f, 0.f, 0.f, 0.f};
  f32x4 o[4] = {fzero, fzero, fzero, fzero};
  float mrow[4] = {-INFINITY, -INFINITY, -INFINITY, -INFINITY};
  float lrow[4] = {0.f, 0.f, 0.f, 0.f};

  bf16x8 kA[8], vA[8], kB[8], vB[8];

  auto loadKV = [&](bf16x8 (&kf)[8], bf16x8 (&vf)[8], int u) {
    const int k0 = bT + u * 64;
#pragma unroll
    for (int i = 0; i < 4; ++i) {
      const u16* kp = Kb + (size_t)(k0 + i * 16 + lane16) * 64 + 8 * laneHi;
      kf[i * 2 + 0] = *(const bf16x8*)(kp);
      kf[i * 2 + 1] = *(const bf16x8*)(kp + 32);
      const u16* vp = Vt + (size_t)(i * 16 + lane16) * 16384 + k0 + 8 * laneHi;
      vf[i * 2 + 0] = *(const bf16x8*)(vp);
      vf[i * 2 + 1] = *(const bf16x8*)(vp + 32);
    }
  };

  auto compute = [&](bf16x8 (&kf)[8], bf16x8 (&vf)[8], int u) {
    f32x4 sc[4];
#pragma unroll
    for (int ct = 0; ct < 4; ++ct) {
      f32x4 a = fzero;
      a = MFMA_BF16(qf0, kf[ct * 2 + 0], a, 0, 0, 0);
      a = MFMA_BF16(qf1, kf[ct * 2 + 1], a, 0, 0, 0);
      sc[ct] = a;
    }
    if (u == n64 - 1) {                            // diagonal unit: causal mask
#pragma unroll
      for (int ct = 0; ct < 4; ++ct)
#pragma unroll
        for (int r = 0; r < 4; ++r) {
          const int col = u * 64 + ct * 16 + lane16;
          const int row = q0 + laneHi * 4 + r;
          if (col > row) sc[ct][r] = -INFINITY;
        }
    }
    float mt[4] = {-INFINITY, -INFINITY, -INFINITY, -INFINITY};
#pragma unroll
    for (int ct = 0; ct < 4; ++ct)
#pragma unroll
      for (int r = 0; r < 4; ++r) mt[r] = fmaxf(mt[r], sc[ct][r]);
#pragma unroll
    for (int d = 1; d < 16; d <<= 1)
#pragma unroll
      for (int r = 0; r < 4; ++r) mt[r] = fmaxf(mt[r], __shfl_xor(mt[r], d));

    float alpha[4], rs[4];
#pragma unroll
    for (int r = 0; r < 4; ++r) {
      const float mn = fmaxf(mrow[r], mt[r]);
      alpha[r] = __expf(mrow[r] - mn);
      mrow[r] = mn;
      rs[r] = 0.f;
    }
#pragma unroll
    for (int ct = 0; ct < 4; ++ct)
#pragma unroll
      for (int r = 0; r < 4; ++r) {
        const float pv = __expf(sc[ct][r] - mrow[r]);
        rs[r] += pv;
        shP[w][(laneHi * 4 + r) * PLD + ct * 16 + lane16] = f2bf(pv);
      }
#pragma unroll
    for (int d = 1; d < 16; d <<= 1)
#pragma unroll
      for (int r = 0; r < 4; ++r) rs[r] += __shfl_xor(rs[r], d);
#pragma unroll
    for (int r = 0; r < 4; ++r) lrow[r] = lrow[r] * alpha[r] + rs[r];
#pragma unroll
    for (int nt = 0; nt < 4; ++nt)
#pragma unroll
      for (int r = 0; r < 4; ++r) o[nt][r] *= alpha[r];

    asm volatile("s_waitcnt lgkmcnt(0)" ::: "memory");  // wave-local P round-trip

#pragma unroll
    for (int kk = 0; kk < 2; ++kk) {
      bf16x8 pa = *(const bf16x8*)&shP[w][lane16 * PLD + kk * 32 + 8 * laneHi];
#pragma unroll
      for (int nt = 0; nt < 4; ++nt)
        o[nt] = MFMA_BF16(pa, vf[nt * 2 + kk], o[nt], 0, 0, 0);
    }
  };

  // main loop: manual 2x unroll with double-buffered K/V fragment registers
  int u = s;
  if (u < e) loadKV(kA, vA, u);
  while (u < e) {
    if (u + 1 < e) loadKV(kB, vB, u + 1);
    compute(kA, vA, u);
    ++u;
    if (u >= e) break;
    if (u + 1 < e) loadKV(kA, vA, u + 1);
    compute(kB, vB, u);
    ++u;
  }

  // combine: waves 1..3 publish partials, wave 0 merges + writes out
  if (w > 0) {
    float* dst = &shC[w - 1][l][0];
#pragma unroll
    for (int r = 0; r < 4; ++r) { dst[r] = mrow[r]; dst[4 + r] = lrow[r]; }
#pragma unroll
    for (int nt = 0; nt < 4; ++nt)
#pragma unroll
      for (int r = 0; r < 4; ++r) dst[8 + nt * 4 + r] = o[nt][r];
  }
  __syncthreads();
  if (w == 0) {
#pragma unroll
    for (int peer = 0; peer < 3; ++peer) {
      const float* src = &shC[peer][l][0];
#pragma unroll
      for (int r = 0; r < 4; ++r) {
        const float pm = src[r], pl = src[4 + r];
        const float mn = fmaxf(mrow[r], pm);
        // fmaxf(-inf - -inf = NaN, -80) -> -80 : branchless guard for empty partials
        const float aS = __expf(fmaxf(mrow[r] - mn, -80.f));
        const float aP = __expf(fmaxf(pm - mn, -80.f));
        mrow[r] = mn;
        lrow[r] = lrow[r] * aS + pl * aP;
#pragma unroll
        for (int nt = 0; nt < 4; ++nt)
          o[nt][r] = o[nt][r] * aS + src[8 + nt * 4 + r] * aP;
      }
    }
    float inv[4];
#pragma unroll
    for (int r = 0; r < 4; ++r) inv[r] = 1.0f / lrow[r];
#pragma unroll
    for (int nt = 0; nt < 4; ++nt)
#pragma unroll
      for (int r = 0; r < 4; ++r)
        out[(size_t)(bT + q0 + laneHi * 4 + r) * 64 + nt * 16 + lane16] = o[nt][r] * inv[r];
  }
}

extern "C" void kernel_launch(void* const* d_in, const int* in_sizes, int n_in,
                              void* d_out, int out_size, void* d_ws, size_t ws_size,
                              hipStream_t stream) {
  const float* x  = (const float*)d_in[0];
  const float* Wq = (const float*)d_in[1];
  const float* Wk = (const float*)d_in[2];
  const float* Wv = (const float*)d_in[3];
  float* out = (float*)d_out;

  char* ws = (char*)d_ws;
  u16* Wt = (u16*)ws;                                   // 192*1024*2   = 384 KiB
  u16* Qb = (u16*)(ws + 393216);                        // 16384*64*2   = 2 MiB
  u16* Kb = (u16*)(ws + 393216 + 2097152);
  u16* Vt = (u16*)(ws + 393216 + 2 * 2097152);          // transposed V [64][16384]

  wt_kernel<<<192, 256, 0, stream>>>(Wq, Wk, Wv, Wt);
  qkv2<<<768, 256, 0, stream>>>(x, Wt, Qb, Kb, Vt);
  attn2<<<1024, 256, 0, stream>>>(Qb, Kb, Vt, out);
}

// Round 4
// 151.721 us; speedup vs baseline: 1.5043x; 1.0781x over previous
//
#include <hip/hip_runtime.h>

typedef short bf16x8 __attribute__((ext_vector_type(8)));
typedef float f32x4 __attribute__((ext_vector_type(4)));
typedef float fvec4 __attribute__((ext_vector_type(4)));
typedef unsigned short u16;
typedef unsigned int u32;

#define MFMA_BF16 __builtin_amdgcn_mfma_f32_16x16x32_bf16

static __device__ __forceinline__ u16 f2bf(float f) {
  union { float f; unsigned u; } v; v.f = f;
  return (u16)((v.u + 0x7FFFu + ((v.u >> 16) & 1u)) >> 16);  // RNE
}
static __device__ __forceinline__ u32 pack2bf(float a, float b) {
  return (u32)f2bf(a) | ((u32)f2bf(b) << 16);
}

// ---------------- Kernel 0: W -> Wt[192][1024] bf16; Q gets 1/sqrt(64)*log2(e) folded in
__global__ __launch_bounds__(256) void wt_kernel(const float* __restrict__ Wq,
                                                 const float* __restrict__ Wk,
                                                 const float* __restrict__ Wv,
                                                 u16* __restrict__ Wt) {
  const int nrow = blockIdx.x;               // 0..191
  const int m = nrow >> 6, n = nrow & 63;
  const float* W = (m == 0) ? Wq : ((m == 1) ? Wk : Wv);
  const float s = (m == 0) ? 0.125f * 1.44269504f : 1.0f;  // scores in base-2 units
  for (int k = threadIdx.x; k < 1024; k += 256)
    Wt[(size_t)nrow * 1024 + k] = f2bf(W[(size_t)k * 64 + n] * s);
}

// ---------------- Kernel 1: QKV projection, x read ONCE.
// 1024 blocks x 16 rows. 4 waves share the block's x rows; wave w computes
// global n-subtiles {3w..3w+2} of 12 (Q:0-3, K:4-7, V:8-11; V stored transposed).
__global__ __launch_bounds__(256) void qkv3(const float* __restrict__ x,
                                            const u16* __restrict__ Wt,
                                            u16* __restrict__ Qb,
                                            u16* __restrict__ Kb,
                                            u16* __restrict__ Vt) {
  const int w = threadIdx.x >> 6, l = threadIdx.x & 63;
  const int lane16 = l & 15, laneHi = l >> 4;
  const int r0 = blockIdx.x * 16;
  const float* xrow = x + (size_t)(r0 + lane16) * 1024;
  const int nt0 = w * 3;

  const f32x4 fzero = {0.f, 0.f, 0.f, 0.f};
  f32x4 acc[3] = {fzero, fzero, fzero};

#pragma unroll 2
  for (int kk = 0; kk < 32; ++kk) {
    const int kb = kk * 32 + 8 * laneHi;
    fvec4 f0 = *(const fvec4*)(xrow + kb);
    fvec4 f1 = *(const fvec4*)(xrow + kb + 4);
    bf16x8 a;
#pragma unroll
    for (int j = 0; j < 4; ++j) { a[j] = (short)f2bf(f0[j]); a[j + 4] = (short)f2bf(f1[j]); }
#pragma unroll
    for (int i = 0; i < 3; ++i) {
      bf16x8 bfrag = *(const bf16x8*)(Wt + (size_t)((nt0 + i) * 16 + lane16) * 1024 + kb);
      acc[i] = MFMA_BF16(a, bfrag, acc[i], 0, 0, 0);
    }
  }

#pragma unroll
  for (int i = 0; i < 3; ++i) {
    const int nt = nt0 + i;
    if (nt < 4) {
#pragma unroll
      for (int r = 0; r < 4; ++r)
        Qb[(size_t)(r0 + laneHi * 4 + r) * 64 + nt * 16 + lane16] = f2bf(acc[i][r]);
    } else if (nt < 8) {
#pragma unroll
      for (int r = 0; r < 4; ++r)
        Kb[(size_t)(r0 + laneHi * 4 + r) * 64 + (nt - 4) * 16 + lane16] = f2bf(acc[i][r]);
    } else {
      const int d = (nt - 8) * 16 + lane16;
      uint2 v;
      v.x = pack2bf(acc[i][0], acc[i][1]);
      v.y = pack2bf(acc[i][2], acc[i][3]);
      *(uint2*)(Vt + (size_t)d * 16384 + r0 + laneHi * 4) = v;
    }
  }
}

// ---------------- Kernel 2: causal flash attention, register-direct K/V.
// Grid 1024. j=idx>>2 selects q-tile via balanced map: CU's 4 resident blocks
// get t = {255-r, r, 191-r, 64+r} (sum 510 = const) -> uniform per-CU work.
// 4 waves split the causal KV range; LDS flash-combine at the end.
#define PLD 72

__global__ __launch_bounds__(256) void attn3(const u16* __restrict__ Qb,
                                             const u16* __restrict__ Kb,
                                             const u16* __restrict__ Vt,
                                             float* __restrict__ out) {
  __shared__ __align__(16) u16 shP[4][16 * PLD];   // per-wave P scratch
  __shared__ float shC[3][64][24];                 // waves 1..3 partials

  const int tid = threadIdx.x, w = tid >> 6, l = tid & 63;
  const int lane16 = l & 15, laneHi = l >> 4;
  const int b = blockIdx.x & 3;
  const int j = blockIdx.x >> 2;
  const int g = j >> 6, r_ = j & 63;
  const int t = (g == 0) ? (255 - r_) : (g == 1) ? r_ : (g == 2) ? (191 - r_) : (64 + r_);
  const int q0 = t * 16, bT = b * 4096;

  const u16* qrow = Qb + (size_t)(bT + q0 + lane16) * 64;
  const bf16x8 qf0 = *(const bf16x8*)(qrow + 8 * laneHi);
  const bf16x8 qf1 = *(const bf16x8*)(qrow + 32 + 8 * laneHi);

  const int n64 = (t + 4) >> 2;                    // ceil((t+1)/4) 64-key units
  const int s = (n64 * w) >> 2, e = (n64 * (w + 1)) >> 2;

  const f32x4 fzero = {0.f, 0.f, 0.f, 0.f};
  f32x4 o[4] = {fzero, fzero, fzero, fzero};
  float mrow[4] = {-INFINITY, -INFINITY, -INFINITY, -INFINITY};
  float lrow[4] = {0.f, 0.f, 0.f, 0.f};

  bf16x8 kA[8], vA[8], kB[8], vB[8];

  auto loadKV = [&](bf16x8 (&kf)[8], bf16x8 (&vf)[8], int u) {
    const int k0 = bT + u * 64;
#pragma unroll
    for (int i = 0; i < 4; ++i) {
      const u16* kp = Kb + (size_t)(k0 + i * 16 + lane16) * 64 + 8 * laneHi;
      kf[i * 2 + 0] = *(const bf16x8*)(kp);
      kf[i * 2 + 1] = *(const bf16x8*)(kp + 32);
      const u16* vp = Vt + (size_t)(i * 16 + lane16) * 16384 + k0 + 8 * laneHi;
      vf[i * 2 + 0] = *(const bf16x8*)(vp);
      vf[i * 2 + 1] = *(const bf16x8*)(vp + 32);
    }
  };

  auto compute = [&](bf16x8 (&kf)[8], bf16x8 (&vf)[8], int u) {
    f32x4 sc[4];
#pragma unroll
    for (int ct = 0; ct < 4; ++ct) {
      f32x4 a = fzero;
      a = MFMA_BF16(qf0, kf[ct * 2 + 0], a, 0, 0, 0);
      a = MFMA_BF16(qf1, kf[ct * 2 + 1], a, 0, 0, 0);
      sc[ct] = a;
    }
    if (u == n64 - 1) {                            // diagonal unit: causal mask
#pragma unroll
      for (int ct = 0; ct < 4; ++ct)
#pragma unroll
        for (int r = 0; r < 4; ++r) {
          const int col = u * 64 + ct * 16 + lane16;
          const int row = q0 + laneHi * 4 + r;
          if (col > row) sc[ct][r] = -INFINITY;
        }
    }
    float mt[4] = {-INFINITY, -INFINITY, -INFINITY, -INFINITY};
#pragma unroll
    for (int ct = 0; ct < 4; ++ct)
#pragma unroll
      for (int r = 0; r < 4; ++r) mt[r] = fmaxf(mt[r], sc[ct][r]);
#pragma unroll
    for (int d = 1; d < 16; d <<= 1)
#pragma unroll
      for (int r = 0; r < 4; ++r) mt[r] = fmaxf(mt[r], __shfl_xor(mt[r], d));

    float alpha[4], rs[4];
#pragma unroll
    for (int r = 0; r < 4; ++r) {
      const float mn = fmaxf(mrow[r], mt[r]);
      alpha[r] = exp2f(mrow[r] - mn);              // base-2 throughout
      mrow[r] = mn;
      rs[r] = 0.f;
    }
#pragma unroll
    for (int ct = 0; ct < 4; ++ct)
#pragma unroll
      for (int r = 0; r < 4; ++r) {
        const float pv = exp2f(sc[ct][r] - mrow[r]);
        rs[r] += pv;
        shP[w][(laneHi * 4 + r) * PLD + ct * 16 + lane16] = f2bf(pv);
      }
#pragma unroll
    for (int d = 1; d < 16; d <<= 1)
#pragma unroll
      for (int r = 0; r < 4; ++r) rs[r] += __shfl_xor(rs[r], d);
#pragma unroll
    for (int r = 0; r < 4; ++r) lrow[r] = lrow[r] * alpha[r] + rs[r];
#pragma unroll
    for (int nt = 0; nt < 4; ++nt)
#pragma unroll
      for (int r = 0; r < 4; ++r) o[nt][r] *= alpha[r];

    asm volatile("s_waitcnt lgkmcnt(0)" ::: "memory");  // wave-local P round-trip

#pragma unroll
    for (int kk = 0; kk < 2; ++kk) {
      bf16x8 pa = *(const bf16x8*)&shP[w][lane16 * PLD + kk * 32 + 8 * laneHi];
#pragma unroll
      for (int nt = 0; nt < 4; ++nt)
        o[nt] = MFMA_BF16(pa, vf[nt * 2 + kk], o[nt], 0, 0, 0);
    }
  };

  // main loop: 2x unrolled with double-buffered K/V fragment registers
  int u = s;
  if (u < e) loadKV(kA, vA, u);
  while (u < e) {
    if (u + 1 < e) loadKV(kB, vB, u + 1);
    compute(kA, vA, u);
    ++u;
    if (u >= e) break;
    if (u + 1 < e) loadKV(kA, vA, u + 1);
    compute(kB, vB, u);
    ++u;
  }

  // combine: waves 1..3 publish partials, wave 0 merges + writes out
  if (w > 0) {
    float* dst = &shC[w - 1][l][0];
#pragma unroll
    for (int r = 0; r < 4; ++r) { dst[r] = mrow[r]; dst[4 + r] = lrow[r]; }
#pragma unroll
    for (int nt = 0; nt < 4; ++nt)
#pragma unroll
      for (int r = 0; r < 4; ++r) dst[8 + nt * 4 + r] = o[nt][r];
  }
  __syncthreads();
  if (w == 0) {
#pragma unroll
    for (int peer = 0; peer < 3; ++peer) {
      const float* src = &shC[peer][l][0];
#pragma unroll
      for (int r = 0; r < 4; ++r) {
        const float pm = src[r], pl = src[4 + r];
        const float mn = fmaxf(mrow[r], pm);
        // fmaxf(NaN, -80) -> -80 : branchless guard for empty partials
        const float aS = exp2f(fmaxf(mrow[r] - mn, -80.f));
        const float aP = exp2f(fmaxf(pm - mn, -80.f));
        mrow[r] = mn;
        lrow[r] = lrow[r] * aS + pl * aP;
#pragma unroll
        for (int nt = 0; nt < 4; ++nt)
          o[nt][r] = o[nt][r] * aS + src[8 + nt * 4 + r] * aP;
      }
    }
    float inv[4];
#pragma unroll
    for (int r = 0; r < 4; ++r) inv[r] = 1.0f / lrow[r];
#pragma unroll
    for (int nt = 0; nt < 4; ++nt)
#pragma unroll
      for (int r = 0; r < 4; ++r)
        out[(size_t)(bT + q0 + laneHi * 4 + r) * 64 + nt * 16 + lane16] = o[nt][r] * inv[r];
  }
}

extern "C" void kernel_launch(void* const* d_in, const int* in_sizes, int n_in,
                              void* d_out, int out_size, void* d_ws, size_t ws_size,
                              hipStream_t stream) {
  const float* x  = (const float*)d_in[0];
  const float* Wq = (const float*)d_in[1];
  const float* Wk = (const float*)d_in[2];
  const float* Wv = (const float*)d_in[3];
  float* out = (float*)d_out;

  char* ws = (char*)d_ws;
  u16* Wt = (u16*)ws;                                   // 192*1024*2   = 384 KiB
  u16* Qb = (u16*)(ws + 393216);                        // 16384*64*2   = 2 MiB
  u16* Kb = (u16*)(ws + 393216 + 2097152);
  u16* Vt = (u16*)(ws + 393216 + 2 * 2097152);          // transposed V [64][16384]

  wt_kernel<<<192, 256, 0, stream>>>(Wq, Wk, Wv, Wt);
  qkv3<<<1024, 256, 0, stream>>>(x, Wt, Qb, Kb, Vt);
  attn3<<<1024, 256, 0, stream>>>(Qb, Kb, Vt, out);
}